// Round 2
// baseline (412.190 us; speedup 1.0000x reference)
//
#include <hip/hip_runtime.h>
#include <hip/hip_bf16.h>

#define WINDOW 5
#define DIM 1024
#define FEAT 1024
#define SEQ 128
#define BATCH 128
#define MTOT (BATCH*SEQ)      // 16384
#define NTOT (WINDOW*FEAT)    // 5120
#define KTOT DIM

#define BM 128
#define BN 128
#define BK 64                 // i8 MFMA K=64

typedef int int4v __attribute__((ext_vector_type(4)));

static __device__ __forceinline__ unsigned short f2bf(float f) {
  union { float f; unsigned int i; } c; c.f = f;
  unsigned int i = c.i;
  unsigned int lsb = (i >> 16) & 1u;
  i += 0x7fffu + lsb;            // round-to-nearest-even
  return (unsigned short)(i >> 16);
}
static __device__ __forceinline__ float bf2f(unsigned short u) {
  union { unsigned int i; float f; } c; c.i = ((unsigned int)u) << 16; return c.f;
}
static __device__ __forceinline__ signed char q8(float v, float inv) {
  float q = rintf(v * inv);
  q = fminf(fmaxf(q, -127.f), 127.f);
  return (signed char)(int)q;
}

// ---------------- x fp32 -> i8 with per-row scale ----------------
__global__ __launch_bounds__(256) void quant_x(const float* __restrict__ x,
                                               signed char* __restrict__ xq,
                                               float* __restrict__ sx) {
  int row  = blockIdx.x * 4 + (threadIdx.x >> 6);   // one wave per row
  int lane = threadIdx.x & 63;
  const float* xr = x + (size_t)row * KTOT;

  float4 v[4];
  float amax = 0.f;
  #pragma unroll
  for (int i = 0; i < 4; i++) {
    v[i] = ((const float4*)xr)[i * 64 + lane];
    amax = fmaxf(amax, fmaxf(fmaxf(fabsf(v[i].x), fabsf(v[i].y)),
                             fmaxf(fabsf(v[i].z), fabsf(v[i].w))));
  }
  #pragma unroll
  for (int m = 1; m < 64; m <<= 1)
    amax = fmaxf(amax, __shfl_xor(amax, m));

  float inv = amax > 0.f ? 127.f / amax : 0.f;
  int* xqr = (int*)(xq + (size_t)row * KTOT);
  #pragma unroll
  for (int i = 0; i < 4; i++) {
    int p = ((int)(unsigned char)q8(v[i].x, inv)) |
            ((int)(unsigned char)q8(v[i].y, inv) << 8) |
            ((int)(unsigned char)q8(v[i].z, inv) << 16) |
            ((int)q8(v[i].w, inv) << 24);
    xqr[i * 64 + lane] = p;
  }
  if (lane == 0) sx[row] = amax / 127.f;
}

// ---------------- per-(w,f) column absmax of Ws ----------------
__global__ __launch_bounds__(256) void w_colamax(const float* __restrict__ Ws,
                                                 float* __restrict__ sw) {
  int idx = blockIdx.x * 256 + threadIdx.x;   // w*1024 + f, 5120 total
  int w = idx >> 10, f = idx & 1023;
  const float* p = Ws + (size_t)w * DIM * FEAT + f;
  float amax = 0.f;
  for (int d = 0; d < DIM; d++)
    amax = fmaxf(amax, fabsf(p[(size_t)d * FEAT]));
  sw[idx] = amax / 127.f;
}

// ---------------- Ws[w][d][f] fp32 -> WqT[w][f][d] i8 ----------------
__global__ __launch_bounds__(256) void transq_ws(const float* __restrict__ Ws,
                                                 const float* __restrict__ sw,
                                                 signed char* __restrict__ wq) {
  __shared__ float tile[32][33];
  int w  = blockIdx.z;
  int f0 = blockIdx.x * 32, d0 = blockIdx.y * 32;
  int tx = threadIdx.x, ty = threadIdx.y;       // (32,8)
  const float* src = Ws + ((size_t)w * DIM + d0) * FEAT + f0;
  #pragma unroll
  for (int i = 0; i < 4; i++)
    tile[ty + 8*i][tx] = src[(size_t)(ty + 8*i) * FEAT + tx];
  __syncthreads();
  signed char* dst = wq + ((size_t)w * FEAT + f0) * DIM + d0;
  #pragma unroll
  for (int i = 0; i < 4; i++) {
    int f = f0 + ty + 8*i;
    float swv = sw[(w << 10) + f];
    float inv = swv > 0.f ? 1.0f / swv : 0.f;
    dst[(size_t)(ty + 8*i) * DIM + tx] = q8(tile[tx][ty + 8*i], inv);
  }
}

// ---------------- GEMM i8: proj = dequant(xq @ wqT), bf16 out ----------------
__global__ __launch_bounds__(256) void gemm_i8(
    const signed char* __restrict__ xq,   // [MTOT][KTOT] i8
    const signed char* __restrict__ wq,   // [W*FEAT][DIM] i8 (K-contiguous)
    const float* __restrict__ sx,         // [MTOT]
    const float* __restrict__ sw,         // [W*FEAT]
    unsigned short* __restrict__ proj,    // [chunk_rows][NTOT] bf16, chunk-local
    int m_base)
{
  __shared__ signed char As[BM * BK];   // [128][64] linear, 8KB
  __shared__ signed char Bs[BN * BK];   // [128][64] linear, 8KB

  const int tid  = threadIdx.x;
  const int wid  = tid >> 6;
  const int lane = tid & 63;

  const int mt = blockIdx.x;
  const int n0 = blockIdx.y * BN;

  const signed char* aG = xq + (size_t)(m_base + mt * BM) * KTOT;
  const signed char* bG = wq + (size_t)n0 * DIM;

  // staging: 1KB segment = 16 rows x 64B; lane l -> row l/4, byte (l%4)*16
  const int r_seg = lane >> 2;
  const int c16   = (lane & 3) << 4;

  int4v acc[4][4];
  #pragma unroll
  for (int i = 0; i < 4; i++)
    #pragma unroll
    for (int j = 0; j < 4; j++)
      acc[i][j] = (int4v){0, 0, 0, 0};

  const int wm = wid >> 1, wn = wid & 1;   // 2x2 waves, 64x64 each
  const int fr_row = lane & 15;
  const int fr_k   = (lane >> 4) << 4;     // 0,16,32,48 (16 consecutive i8 per lane)

  for (int kt = 0; kt < KTOT / BK; kt++) {
    const int k0 = kt * BK;
    {
      int s0 = wid, s1 = wid + 4;
      __builtin_amdgcn_global_load_lds(
          (const __attribute__((address_space(1))) void*)(aG + (size_t)(s0*16 + r_seg)*KTOT + k0 + c16),
          (__attribute__((address_space(3))) void*)(As + s0*1024), 16, 0, 0);
      __builtin_amdgcn_global_load_lds(
          (const __attribute__((address_space(1))) void*)(aG + (size_t)(s1*16 + r_seg)*KTOT + k0 + c16),
          (__attribute__((address_space(3))) void*)(As + s1*1024), 16, 0, 0);
      __builtin_amdgcn_global_load_lds(
          (const __attribute__((address_space(1))) void*)(bG + (size_t)(s0*16 + r_seg)*DIM + k0 + c16),
          (__attribute__((address_space(3))) void*)(Bs + s0*1024), 16, 0, 0);
      __builtin_amdgcn_global_load_lds(
          (const __attribute__((address_space(1))) void*)(bG + (size_t)(s1*16 + r_seg)*DIM + k0 + c16),
          (__attribute__((address_space(3))) void*)(Bs + s1*1024), 16, 0, 0);
    }
    __syncthreads();

    int4v a[4], b[4];
    #pragma unroll
    for (int i = 0; i < 4; i++)
      a[i] = *(const int4v*)(As + (wm*64 + i*16 + fr_row) * BK + fr_k);
    #pragma unroll
    for (int j = 0; j < 4; j++)
      b[j] = *(const int4v*)(Bs + (wn*64 + j*16 + fr_row) * BK + fr_k);

    #pragma unroll
    for (int i = 0; i < 4; i++)
      #pragma unroll
      for (int j = 0; j < 4; j++)
        acc[i][j] = __builtin_amdgcn_mfma_i32_16x16x64_i8(a[i], b[j], acc[i][j], 0, 0, 0);

    __syncthreads();
  }

  // epilogue: C/D layout col=lane&15, row=(lane>>4)*4+reg (dtype-independent)
  const int crow = (lane >> 4) << 2;
  const int ccol = lane & 15;
  unsigned short* outp = proj + (size_t)(mt * BM) * NTOT + n0;
  #pragma unroll
  for (int i = 0; i < 4; i++) {
    #pragma unroll
    for (int j = 0; j < 4; j++) {
      float swv[1];
      float s_w = sw[n0 + wn*64 + j*16 + ccol];
      (void)swv;
      #pragma unroll
      for (int r = 0; r < 4; r++) {
        int mrow = wm*64 + i*16 + crow + r;
        int ncol = wn*64 + j*16 + ccol;
        float v = (float)acc[i][j][r] * sx[m_base + mt*BM + mrow] * s_w;
        outp[(size_t)mrow * NTOT + ncol] = f2bf(v);
      }
    }
  }
}

// ---------------- max-plus scan over l + tanh ----------------
__global__ __launch_bounds__(256) void scan_kernel(
    const unsigned short* __restrict__ proj,  // [nbatch*SEQ][NTOT] bf16, chunk-local
    const float* __restrict__ bias,
    float* __restrict__ out, int b_base, int nbatch)
{
  int tid = blockIdx.x * 256 + threadIdx.x;
  int bb  = tid >> 9;                 // local batch (512 threads per batch)
  if (bb >= nbatch) return;
  int f0  = (tid & 511) << 1;         // 2 f's per thread

  const unsigned short* p = proj + (size_t)bb * SEQ * NTOT + f0;

  float h[5][2];
  #pragma unroll
  for (int k = 0; k < 5; k++) { h[k][0] = 0.f; h[k][1] = 0.f; }

  for (int l = 0; l < SEQ; l++) {
    float pw[5][2];
    #pragma unroll
    for (int w = 0; w < 5; w++) {
      unsigned int v = *(const unsigned int*)(p + (size_t)l * NTOT + (w << 10));
      pw[w][0] = bf2f((unsigned short)(v & 0xffffu));
      pw[w][1] = bf2f((unsigned short)(v >> 16));
    }
    #pragma unroll
    for (int c = 0; c < 2; c++) {
      h[4][c] = fmaxf(h[3][c] + pw[4][c], h[4][c]);
      h[3][c] = fmaxf(h[2][c] + pw[3][c], h[3][c]);
      h[2][c] = fmaxf(h[1][c] + pw[2][c], h[2][c]);
      h[1][c] = fmaxf(h[0][c] + pw[1][c], h[1][c]);
      h[0][c] = fmaxf(pw[0][c],          h[0][c]);
    }
  }
  float b0 = bias[f0], b1 = bias[f0 + 1];
  size_t ob = (size_t)(b_base + bb) * FEAT + f0;
  out[ob]     = tanhf(h[4][0] + b0);
  out[ob + 1] = tanhf(h[4][1] + b1);
}

extern "C" void kernel_launch(void* const* d_in, const int* in_sizes, int n_in,
                              void* d_out, int out_size, void* d_ws, size_t ws_size,
                              hipStream_t stream) {
  const float* x  = (const float*)d_in[0];
  const float* Ws = (const float*)d_in[1];
  const float* b  = (const float*)d_in[2];
  float* out = (float*)d_out;

  char* ws = (char*)d_ws;
  const size_t XQ_BYTES = (size_t)MTOT * KTOT;            // 16,777,216
  const size_t WQ_BYTES = (size_t)WINDOW * FEAT * DIM;    //  5,242,880
  const size_t SX_BYTES = (size_t)MTOT * 4;               //     65,536
  const size_t SW_BYTES = (size_t)WINDOW * FEAT * 4;      //     20,480
  signed char* xq = (signed char*)ws;
  signed char* wq = (signed char*)(ws + XQ_BYTES);
  float* sx = (float*)(ws + XQ_BYTES + WQ_BYTES);
  float* sw = (float*)(ws + XQ_BYTES + WQ_BYTES + SX_BYTES);
  char* projbase = ws + XQ_BYTES + WQ_BYTES + SX_BYTES + SW_BYTES;
  const size_t HEAD = XQ_BYTES + WQ_BYTES + SX_BYTES + SW_BYTES;

  const size_t per_batch = (size_t)SEQ * NTOT * 2;        // 1,310,720
  size_t avail = (ws_size > HEAD) ? (ws_size - HEAD) : per_batch;
  int nb = (int)(avail / per_batch);
  if (nb > BATCH) nb = BATCH;
  if (nb < 1) nb = 1;

  hipLaunchKernelGGL(quant_x, dim3(MTOT / 4), dim3(256), 0, stream, x, xq, sx);
  hipLaunchKernelGGL(w_colamax, dim3(NTOT / 256), dim3(256), 0, stream, Ws, sw);
  hipLaunchKernelGGL(transq_ws, dim3(FEAT / 32, DIM / 32, WINDOW), dim3(32, 8), 0, stream,
                     Ws, sw, wq);

  for (int done = 0; done < BATCH; done += nb) {
    int cur = (BATCH - done < nb) ? (BATCH - done) : nb;
    unsigned short* proj = (unsigned short*)projbase;
    hipLaunchKernelGGL(gemm_i8, dim3(cur, NTOT / BN), dim3(256), 0, stream,
                       xq, wq, sx, sw, proj, done * SEQ);
    hipLaunchKernelGGL(scan_kernel, dim3(cur * 2), dim3(256), 0, stream,
                       proj, b, out, done, cur);
  }
}

// Round 3
// 200.866 us; speedup vs baseline: 2.0521x; 2.0521x over previous
//
#include <hip/hip_runtime.h>
#include <hip/hip_bf16.h>

#define WINDOW 5
#define DIM 1024
#define FEAT 1024
#define SEQ 128
#define BATCH 128
#define MTOT (BATCH*SEQ)      // 16384
#define NTOT (WINDOW*FEAT)    // 5120
#define KTOT DIM

#define BM 128
#define BN 128
#define BK 64                 // i8 MFMA K=64
#define DCHUNK 16             // d-rows per partial-absmax block

typedef int int4v __attribute__((ext_vector_type(4)));

static __device__ __forceinline__ unsigned short f2bf(float f) {
  union { float f; unsigned int i; } c; c.f = f;
  unsigned int i = c.i;
  unsigned int lsb = (i >> 16) & 1u;
  i += 0x7fffu + lsb;            // round-to-nearest-even
  return (unsigned short)(i >> 16);
}
static __device__ __forceinline__ float bf2f(unsigned short u) {
  union { unsigned int i; float f; } c; c.i = ((unsigned int)u) << 16; return c.f;
}
static __device__ __forceinline__ signed char q8(float v, float inv) {
  float q = rintf(v * inv);
  q = fminf(fmaxf(q, -127.f), 127.f);
  return (signed char)(int)q;
}

// ---------------- x fp32 -> i8 with per-row scale ----------------
__global__ __launch_bounds__(256) void quant_x(const float* __restrict__ x,
                                               signed char* __restrict__ xq,
                                               float* __restrict__ sx) {
  int row  = blockIdx.x * 4 + (threadIdx.x >> 6);   // one wave per row
  int lane = threadIdx.x & 63;
  const float* xr = x + (size_t)row * KTOT;

  float4 v[4];
  float amax = 0.f;
  #pragma unroll
  for (int i = 0; i < 4; i++) {
    v[i] = ((const float4*)xr)[i * 64 + lane];
    amax = fmaxf(amax, fmaxf(fmaxf(fabsf(v[i].x), fabsf(v[i].y)),
                             fmaxf(fabsf(v[i].z), fabsf(v[i].w))));
  }
  #pragma unroll
  for (int m = 1; m < 64; m <<= 1)
    amax = fmaxf(amax, __shfl_xor(amax, m));

  float inv = amax > 0.f ? 127.f / amax : 0.f;
  int* xqr = (int*)(xq + (size_t)row * KTOT);
  #pragma unroll
  for (int i = 0; i < 4; i++) {
    int p = ((int)(unsigned char)q8(v[i].x, inv)) |
            ((int)(unsigned char)q8(v[i].y, inv) << 8) |
            ((int)(unsigned char)q8(v[i].z, inv) << 16) |
            ((int)q8(v[i].w, inv) << 24);
    xqr[i * 64 + lane] = p;
  }
  if (lane == 0) sx[row] = amax / 127.f;
}

// ---------------- per-(w,f) column absmax, stage 1: coalesced partials ----------------
// grid (1, DIM/DCHUNK, WINDOW), block 256; thread t covers f = 4t..4t+3 via float4
__global__ __launch_bounds__(256) void w_colamax_part(const float* __restrict__ Ws,
                                                      float* __restrict__ part) {
  int w  = blockIdx.z;
  int dc = blockIdx.y;
  int f4 = threadIdx.x;
  const float* p = Ws + ((size_t)w * DIM + (size_t)dc * DCHUNK) * FEAT;
  float4 m = {0.f, 0.f, 0.f, 0.f};
  #pragma unroll
  for (int d = 0; d < DCHUNK; d++) {
    float4 v = ((const float4*)(p + (size_t)d * FEAT))[f4];
    m.x = fmaxf(m.x, fabsf(v.x));
    m.y = fmaxf(m.y, fabsf(v.y));
    m.z = fmaxf(m.z, fabsf(v.z));
    m.w = fmaxf(m.w, fabsf(v.w));
  }
  ((float4*)(part + ((size_t)w * (DIM / DCHUNK) + dc) * FEAT))[f4] = m;
}

// ---------------- stage 2: fold partials -> sw = amax/127 ----------------
__global__ __launch_bounds__(256) void w_colamax_reduce(const float* __restrict__ part,
                                                        float* __restrict__ sw) {
  int idx = blockIdx.x * 256 + threadIdx.x;   // w*1024 + f, 5120 total
  int w = idx >> 10, f = idx & 1023;
  const float* p = part + (size_t)w * (DIM / DCHUNK) * FEAT + f;
  float m = 0.f;
  #pragma unroll 8
  for (int c = 0; c < DIM / DCHUNK; c++)
    m = fmaxf(m, p[(size_t)c * FEAT]);
  sw[idx] = m / 127.f;
}

// ---------------- Ws[w][d][f] fp32 -> WqT[w][f][d] i8 ----------------
__global__ __launch_bounds__(256) void transq_ws(const float* __restrict__ Ws,
                                                 const float* __restrict__ sw,
                                                 signed char* __restrict__ wq) {
  __shared__ float tile[32][33];
  int w  = blockIdx.z;
  int f0 = blockIdx.x * 32, d0 = blockIdx.y * 32;
  int tx = threadIdx.x, ty = threadIdx.y;       // (32,8)
  const float* src = Ws + ((size_t)w * DIM + d0) * FEAT + f0;
  #pragma unroll
  for (int i = 0; i < 4; i++)
    tile[ty + 8*i][tx] = src[(size_t)(ty + 8*i) * FEAT + tx];
  __syncthreads();
  signed char* dst = wq + ((size_t)w * FEAT + f0) * DIM + d0;
  #pragma unroll
  for (int i = 0; i < 4; i++) {
    int f = f0 + ty + 8*i;
    float swv = sw[(w << 10) + f];
    float inv = swv > 0.f ? 1.0f / swv : 0.f;
    dst[(size_t)(ty + 8*i) * DIM + tx] = q8(tile[tx][ty + 8*i], inv);
  }
}

// ---------------- GEMM i8: proj = dequant(xq @ wqT), bf16 out ----------------
__global__ __launch_bounds__(256) void gemm_i8(
    const signed char* __restrict__ xq,   // [MTOT][KTOT] i8
    const signed char* __restrict__ wq,   // [W*FEAT][DIM] i8 (K-contiguous)
    const float* __restrict__ sx,         // [MTOT]
    const float* __restrict__ sw,         // [W*FEAT]
    unsigned short* __restrict__ proj,    // [chunk_rows][NTOT] bf16, chunk-local
    int m_base)
{
  __shared__ signed char As[BM * BK];   // [128][64] linear, 8KB
  __shared__ signed char Bs[BN * BK];   // [128][64] linear, 8KB

  const int tid  = threadIdx.x;
  const int wid  = tid >> 6;
  const int lane = tid & 63;

  const int mt = blockIdx.x;
  const int n0 = blockIdx.y * BN;

  const signed char* aG = xq + (size_t)(m_base + mt * BM) * KTOT;
  const signed char* bG = wq + (size_t)n0 * DIM;

  // staging: 1KB segment = 16 rows x 64B; lane l -> row l/4, byte (l%4)*16
  const int r_seg = lane >> 2;
  const int c16   = (lane & 3) << 4;

  int4v acc[4][4];
  #pragma unroll
  for (int i = 0; i < 4; i++)
    #pragma unroll
    for (int j = 0; j < 4; j++)
      acc[i][j] = (int4v){0, 0, 0, 0};

  const int wm = wid >> 1, wn = wid & 1;   // 2x2 waves, 64x64 each
  const int fr_row = lane & 15;
  const int fr_k   = (lane >> 4) << 4;     // 0,16,32,48 (16 consecutive i8 per lane)

  for (int kt = 0; kt < KTOT / BK; kt++) {
    const int k0 = kt * BK;
    {
      int s0 = wid, s1 = wid + 4;
      __builtin_amdgcn_global_load_lds(
          (const __attribute__((address_space(1))) void*)(aG + (size_t)(s0*16 + r_seg)*KTOT + k0 + c16),
          (__attribute__((address_space(3))) void*)(As + s0*1024), 16, 0, 0);
      __builtin_amdgcn_global_load_lds(
          (const __attribute__((address_space(1))) void*)(aG + (size_t)(s1*16 + r_seg)*KTOT + k0 + c16),
          (__attribute__((address_space(3))) void*)(As + s1*1024), 16, 0, 0);
      __builtin_amdgcn_global_load_lds(
          (const __attribute__((address_space(1))) void*)(bG + (size_t)(s0*16 + r_seg)*DIM + k0 + c16),
          (__attribute__((address_space(3))) void*)(Bs + s0*1024), 16, 0, 0);
      __builtin_amdgcn_global_load_lds(
          (const __attribute__((address_space(1))) void*)(bG + (size_t)(s1*16 + r_seg)*DIM + k0 + c16),
          (__attribute__((address_space(3))) void*)(Bs + s1*1024), 16, 0, 0);
    }
    __syncthreads();

    int4v a[4], b[4];
    #pragma unroll
    for (int i = 0; i < 4; i++)
      a[i] = *(const int4v*)(As + (wm*64 + i*16 + fr_row) * BK + fr_k);
    #pragma unroll
    for (int j = 0; j < 4; j++)
      b[j] = *(const int4v*)(Bs + (wn*64 + j*16 + fr_row) * BK + fr_k);

    #pragma unroll
    for (int i = 0; i < 4; i++)
      #pragma unroll
      for (int j = 0; j < 4; j++)
        acc[i][j] = __builtin_amdgcn_mfma_i32_16x16x64_i8(a[i], b[j], acc[i][j], 0, 0, 0);

    __syncthreads();
  }

  // epilogue: C/D layout col=lane&15, row=(lane>>4)*4+reg (dtype-independent)
  const int crow = (lane >> 4) << 2;
  const int ccol = lane & 15;
  unsigned short* outp = proj + (size_t)(mt * BM) * NTOT + n0;
  #pragma unroll
  for (int i = 0; i < 4; i++) {
    #pragma unroll
    for (int j = 0; j < 4; j++) {
      float s_w = sw[n0 + wn*64 + j*16 + ccol];
      #pragma unroll
      for (int r = 0; r < 4; r++) {
        int mrow = wm*64 + i*16 + crow + r;
        int ncol = wn*64 + j*16 + ccol;
        float v = (float)acc[i][j][r] * sx[m_base + mt*BM + mrow] * s_w;
        outp[(size_t)mrow * NTOT + ncol] = f2bf(v);
      }
    }
  }
}

// ---------------- max-plus scan over l + tanh ----------------
__global__ __launch_bounds__(256) void scan_kernel(
    const unsigned short* __restrict__ proj,  // [nbatch*SEQ][NTOT] bf16, chunk-local
    const float* __restrict__ bias,
    float* __restrict__ out, int b_base, int nbatch)
{
  int tid = blockIdx.x * 256 + threadIdx.x;
  int bb  = tid >> 9;                 // local batch (512 threads per batch)
  if (bb >= nbatch) return;
  int f0  = (tid & 511) << 1;         // 2 f's per thread

  const unsigned short* p = proj + (size_t)bb * SEQ * NTOT + f0;

  float h[5][2];
  #pragma unroll
  for (int k = 0; k < 5; k++) { h[k][0] = 0.f; h[k][1] = 0.f; }

  for (int l = 0; l < SEQ; l++) {
    float pw[5][2];
    #pragma unroll
    for (int w = 0; w < 5; w++) {
      unsigned int v = *(const unsigned int*)(p + (size_t)l * NTOT + (w << 10));
      pw[w][0] = bf2f((unsigned short)(v & 0xffffu));
      pw[w][1] = bf2f((unsigned short)(v >> 16));
    }
    #pragma unroll
    for (int c = 0; c < 2; c++) {
      h[4][c] = fmaxf(h[3][c] + pw[4][c], h[4][c]);
      h[3][c] = fmaxf(h[2][c] + pw[3][c], h[3][c]);
      h[2][c] = fmaxf(h[1][c] + pw[2][c], h[2][c]);
      h[1][c] = fmaxf(h[0][c] + pw[1][c], h[1][c]);
      h[0][c] = fmaxf(pw[0][c],          h[0][c]);
    }
  }
  float b0 = bias[f0], b1 = bias[f0 + 1];
  size_t ob = (size_t)(b_base + bb) * FEAT + f0;
  out[ob]     = tanhf(h[4][0] + b0);
  out[ob + 1] = tanhf(h[4][1] + b1);
}

extern "C" void kernel_launch(void* const* d_in, const int* in_sizes, int n_in,
                              void* d_out, int out_size, void* d_ws, size_t ws_size,
                              hipStream_t stream) {
  const float* x  = (const float*)d_in[0];
  const float* Ws = (const float*)d_in[1];
  const float* b  = (const float*)d_in[2];
  float* out = (float*)d_out;

  char* ws = (char*)d_ws;
  const size_t XQ_BYTES = (size_t)MTOT * KTOT;                  // 16,777,216
  const size_t WQ_BYTES = (size_t)WINDOW * FEAT * DIM;          //  5,242,880
  const size_t SX_BYTES = (size_t)MTOT * 4;                     //     65,536
  const size_t SW_BYTES = (size_t)WINDOW * FEAT * 4;            //     20,480
  const size_t PART_BYTES = (size_t)WINDOW * (DIM / DCHUNK) * FEAT * 4;  // 1,310,720
  signed char* xq = (signed char*)ws;
  signed char* wq = (signed char*)(ws + XQ_BYTES);
  float* sx   = (float*)(ws + XQ_BYTES + WQ_BYTES);
  float* sw   = (float*)(ws + XQ_BYTES + WQ_BYTES + SX_BYTES);
  float* part = (float*)(ws + XQ_BYTES + WQ_BYTES + SX_BYTES + SW_BYTES);
  const size_t HEAD = XQ_BYTES + WQ_BYTES + SX_BYTES + SW_BYTES + PART_BYTES;
  char* projbase = ws + HEAD;

  const size_t per_batch = (size_t)SEQ * NTOT * 2;              // 1,310,720
  size_t avail = (ws_size > HEAD) ? (ws_size - HEAD) : per_batch;
  int nb = (int)(avail / per_batch);
  if (nb > BATCH) nb = BATCH;
  if (nb < 1) nb = 1;

  hipLaunchKernelGGL(quant_x, dim3(MTOT / 4), dim3(256), 0, stream, x, xq, sx);
  hipLaunchKernelGGL(w_colamax_part, dim3(1, DIM / DCHUNK, WINDOW), dim3(256), 0, stream,
                     Ws, part);
  hipLaunchKernelGGL(w_colamax_reduce, dim3(NTOT / 256), dim3(256), 0, stream, part, sw);
  hipLaunchKernelGGL(transq_ws, dim3(FEAT / 32, DIM / 32, WINDOW), dim3(32, 8), 0, stream,
                     Ws, sw, wq);

  for (int done = 0; done < BATCH; done += nb) {
    int cur = (BATCH - done < nb) ? (BATCH - done) : nb;
    unsigned short* proj = (unsigned short*)projbase;
    hipLaunchKernelGGL(gemm_i8, dim3(cur, NTOT / BN), dim3(256), 0, stream,
                       xq, wq, sx, sw, proj, done * SEQ);
    hipLaunchKernelGGL(scan_kernel, dim3(cur * 2), dim3(256), 0, stream,
                       proj, b, out, done, cur);
  }
}

// Round 4
// 174.722 us; speedup vs baseline: 2.3591x; 1.1496x over previous
//
#include <hip/hip_runtime.h>
#include <hip/hip_bf16.h>

#define WINDOW 5
#define DIM 1024
#define FEAT 1024
#define SEQ 128
#define BATCH 128
#define MTOT (BATCH*SEQ)      // 16384
#define NTOT (WINDOW*FEAT)    // 5120
#define KTOT 1024

#define DCHUNK 16             // d-rows per partial-absmax block

typedef int int4v __attribute__((ext_vector_type(4)));

static __device__ __forceinline__ unsigned short f2bf(float f) {
  union { float f; unsigned int i; } c; c.f = f;
  unsigned int i = c.i;
  unsigned int lsb = (i >> 16) & 1u;
  i += 0x7fffu + lsb;            // round-to-nearest-even
  return (unsigned short)(i >> 16);
}
static __device__ __forceinline__ float bf2f(unsigned short u) {
  union { unsigned int i; float f; } c; c.i = ((unsigned int)u) << 16; return c.f;
}
static __device__ __forceinline__ signed char q8(float v, float inv) {
  float q = rintf(v * inv);
  q = fminf(fmaxf(q, -127.f), 127.f);
  return (signed char)(int)q;
}

// ---------------- x fp32 -> i8 with per-row scale ----------------
__global__ __launch_bounds__(256) void quant_x(const float* __restrict__ x,
                                               signed char* __restrict__ xq,
                                               float* __restrict__ sx) {
  int row  = blockIdx.x * 4 + (threadIdx.x >> 6);   // one wave per row
  int lane = threadIdx.x & 63;
  const float* xr = x + (size_t)row * KTOT;

  float4 v[4];
  float amax = 0.f;
  #pragma unroll
  for (int i = 0; i < 4; i++) {
    v[i] = ((const float4*)xr)[i * 64 + lane];
    amax = fmaxf(amax, fmaxf(fmaxf(fabsf(v[i].x), fabsf(v[i].y)),
                             fmaxf(fabsf(v[i].z), fabsf(v[i].w))));
  }
  #pragma unroll
  for (int m = 1; m < 64; m <<= 1)
    amax = fmaxf(amax, __shfl_xor(amax, m));

  float inv = amax > 0.f ? 127.f / amax : 0.f;
  int* xqr = (int*)(xq + (size_t)row * KTOT);
  #pragma unroll
  for (int i = 0; i < 4; i++) {
    int p = ((int)(unsigned char)q8(v[i].x, inv)) |
            ((int)(unsigned char)q8(v[i].y, inv) << 8) |
            ((int)(unsigned char)q8(v[i].z, inv) << 16) |
            ((int)q8(v[i].w, inv) << 24);
    xqr[i * 64 + lane] = p;
  }
  if (lane == 0) sx[row] = amax / 127.f;
}

// ---------------- per-(w,f) column absmax, stage 1: coalesced partials ----------------
__global__ __launch_bounds__(256) void w_colamax_part(const float* __restrict__ Ws,
                                                      float* __restrict__ part) {
  int w  = blockIdx.z;
  int dc = blockIdx.y;
  int f4 = threadIdx.x;
  const float* p = Ws + ((size_t)w * DIM + (size_t)dc * DCHUNK) * FEAT;
  float4 m = {0.f, 0.f, 0.f, 0.f};
  #pragma unroll
  for (int d = 0; d < DCHUNK; d++) {
    float4 v = ((const float4*)(p + (size_t)d * FEAT))[f4];
    m.x = fmaxf(m.x, fabsf(v.x));
    m.y = fmaxf(m.y, fabsf(v.y));
    m.z = fmaxf(m.z, fabsf(v.z));
    m.w = fmaxf(m.w, fabsf(v.w));
  }
  ((float4*)(part + ((size_t)w * (DIM / DCHUNK) + dc) * FEAT))[f4] = m;
}

// ---------------- stage 2: fold partials -> sw = amax/127 ----------------
__global__ __launch_bounds__(256) void w_colamax_reduce(const float* __restrict__ part,
                                                        float* __restrict__ sw) {
  int idx = blockIdx.x * 256 + threadIdx.x;   // w*1024 + f, 5120 total
  int w = idx >> 10, f = idx & 1023;
  const float* p = part + (size_t)w * (DIM / DCHUNK) * FEAT + f;
  float m = 0.f;
  #pragma unroll 8
  for (int c = 0; c < DIM / DCHUNK; c++)
    m = fmaxf(m, p[(size_t)c * FEAT]);
  sw[idx] = m / 127.f;
}

// ---------------- Ws[w][d][f] fp32 -> WqT[w][f][d] i8 ----------------
__global__ __launch_bounds__(256) void transq_ws(const float* __restrict__ Ws,
                                                 const float* __restrict__ sw,
                                                 signed char* __restrict__ wq) {
  __shared__ float tile[32][33];
  int w  = blockIdx.z;
  int f0 = blockIdx.x * 32, d0 = blockIdx.y * 32;
  int tx = threadIdx.x, ty = threadIdx.y;       // (32,8)
  const float* src = Ws + ((size_t)w * DIM + d0) * FEAT + f0;
  #pragma unroll
  for (int i = 0; i < 4; i++)
    tile[ty + 8*i][tx] = src[(size_t)(ty + 8*i) * FEAT + tx];
  __syncthreads();
  signed char* dst = wq + ((size_t)w * FEAT + f0) * DIM + d0;
  #pragma unroll
  for (int i = 0; i < 4; i++) {
    int f = f0 + ty + 8*i;
    float swv = sw[(w << 10) + f];
    float inv = swv > 0.f ? 1.0f / swv : 0.f;
    dst[(size_t)(ty + 8*i) * DIM + tx] = q8(tile[tx][ty + 8*i], inv);
  }
}

// ---------------- fused GEMM(i8) + dequant + max-plus scan + tanh ----------------
// Block: 512 thr (8 waves, 2M x 4N), tile = 128 l-rows (one batch) x 320 cols (5w x 64f).
// LDS: staging A 16KB + B 40KB (K-step BK=128, XOR-swizzled via pre-swizzled global src)
//      unioned with 80KB bf16 proj tile [128 l][320 c] for the in-LDS scan.
__global__ __launch_bounds__(512, 2) void fused_gemm_scan(
    const signed char* __restrict__ xq,   // [MTOT][1024] i8
    const signed char* __restrict__ wq,   // [W*FEAT][1024] i8 (K-contiguous)
    const float* __restrict__ sx,         // [MTOT]
    const float* __restrict__ swp,        // [W*FEAT]
    const float* __restrict__ bias,       // [FEAT]
    float* __restrict__ out)              // [BATCH][FEAT]
{
  __shared__ __align__(16) char smem[81920];
  signed char* As = (signed char*)smem;             // 16 KB: 128 rows x 128 B
  signed char* Bs = (signed char*)(smem + 16384);   // 40 KB: 320 rows x 128 B

  const int tid  = threadIdx.x;
  const int wid  = tid >> 6;
  const int lane = tid & 63;

  // XCD-chunked swizzle (2048 % 8 == 0 -> bijective); work = b*16 + fslice
  int bid = blockIdx.x;
  int wg  = ((bid & 7) << 8) + (bid >> 3);
  const int b  = wg >> 4;
  const int f0 = (wg & 15) << 6;

  const signed char* aG = xq + (size_t)b * SEQ * KTOT;

  const int wm = wid >> 2, wn = wid & 3;     // wave tile: 64 M x 80 N
  const int rowin = lane >> 3;               // row within 1KB/8-row segment
  const int swb16 = ((lane & 7) ^ rowin) << 4;  // pre-swizzled byte slot in 128B row

  int4v acc[4][5];
  #pragma unroll
  for (int i = 0; i < 4; i++)
    #pragma unroll
    for (int j = 0; j < 5; j++)
      acc[i][j] = (int4v){0, 0, 0, 0};

  for (int kt = 0; kt < 8; kt++) {
    const int k0 = kt << 7;
    // 56 segments (16 A + 40 B), 7 per wave; LDS dest linear, global src pre-swizzled
    #pragma unroll
    for (int c = 0; c < 7; c++) {
      int seg = wid * 7 + c;
      if (seg < 16) {
        int row = (seg << 3) + rowin;      // 0..127
        __builtin_amdgcn_global_load_lds(
            (const __attribute__((address_space(1))) void*)(aG + (size_t)row * KTOT + k0 + swb16),
            (__attribute__((address_space(3))) void*)(As + (seg << 10)), 16, 0, 0);
      } else {
        int sb = seg - 16;
        int r  = (sb << 3) + rowin;        // 0..319: c-index = w*64+fl
        const signed char* src = wq
            + ((size_t)(((r >> 6) << 10) + f0 + (r & 63))) * KTOT + k0 + swb16;
        __builtin_amdgcn_global_load_lds(
            (const __attribute__((address_space(1))) void*)src,
            (__attribute__((address_space(3))) void*)(Bs + (sb << 10)), 16, 0, 0);
      }
    }
    __syncthreads();

    #pragma unroll
    for (int kk = 0; kk < 2; kk++) {
      int4v a[4], bf[5];
      #pragma unroll
      for (int i = 0; i < 4; i++) {
        int row  = wm * 64 + i * 16 + (lane & 15);
        int slot = (lane >> 4) + (kk << 2);
        a[i] = *(const int4v*)(As + row * 128 + ((slot ^ (row & 7)) << 4));
      }
      #pragma unroll
      for (int j = 0; j < 5; j++) {
        int row  = wn * 80 + j * 16 + (lane & 15);
        int slot = (lane >> 4) + (kk << 2);
        bf[j] = *(const int4v*)(Bs + row * 128 + ((slot ^ (row & 7)) << 4));
      }
      #pragma unroll
      for (int i = 0; i < 4; i++)
        #pragma unroll
        for (int j = 0; j < 5; j++)
          acc[i][j] = __builtin_amdgcn_mfma_i32_16x16x64_i8(a[i], bf[j], acc[i][j], 0, 0, 0);
    }
    __syncthreads();
  }

  // ---- dequant -> bf16 proj tile in LDS [128][320], byte addr ^ ((l>>2)&3)<<5 ----
  float sxv[16];
  #pragma unroll
  for (int i = 0; i < 4; i++)
    #pragma unroll
    for (int r = 0; r < 4; r++)
      sxv[i * 4 + r] = sx[b * SEQ + wm * 64 + i * 16 + ((lane >> 4) << 2) + r];
  float swv[5];
  #pragma unroll
  for (int j = 0; j < 5; j++) {
    int c = wn * 80 + j * 16 + (lane & 15);
    swv[j] = swp[((c >> 6) << 10) + f0 + (c & 63)];
  }

  #pragma unroll
  for (int i = 0; i < 4; i++) {
    #pragma unroll
    for (int j = 0; j < 5; j++) {
      #pragma unroll
      for (int r = 0; r < 4; r++) {
        int l = wm * 64 + i * 16 + ((lane >> 4) << 2) + r;
        int c = wn * 80 + j * 16 + (lane & 15);
        float v = (float)acc[i][j][r] * sxv[i * 4 + r] * swv[j];
        int byte = ((l * 320 + c) << 1) ^ (((l >> 2) & 3) << 5);
        *(unsigned short*)(smem + byte) = f2bf(v);
      }
    }
  }
  __syncthreads();

  // ---- max-plus scan over l, one thread per f-column ----
  if (tid < 64) {
    const int fl = tid;
    float h0 = 0.f, h1 = 0.f, h2 = 0.f, h3 = 0.f, h4 = 0.f;
    for (int l = 0; l < SEQ; l++) {
      const int swz  = ((l >> 2) & 3) << 5;
      const int base = l * 640;
      float p[5];
      #pragma unroll
      for (int w = 0; w < 5; w++) {
        int byte = (base + (((w << 6) + fl) << 1)) ^ swz;
        p[w] = bf2f(*(const unsigned short*)(smem + byte));
      }
      h4 = fmaxf(h3 + p[4], h4);
      h3 = fmaxf(h2 + p[3], h3);
      h2 = fmaxf(h1 + p[2], h2);
      h1 = fmaxf(h0 + p[1], h1);
      h0 = fmaxf(p[0], h0);
    }
    out[b * FEAT + f0 + fl] = tanhf(h4 + bias[f0 + fl]);
  }
}

extern "C" void kernel_launch(void* const* d_in, const int* in_sizes, int n_in,
                              void* d_out, int out_size, void* d_ws, size_t ws_size,
                              hipStream_t stream) {
  const float* x  = (const float*)d_in[0];
  const float* Ws = (const float*)d_in[1];
  const float* b  = (const float*)d_in[2];
  float* out = (float*)d_out;

  char* ws = (char*)d_ws;
  const size_t XQ_BYTES = (size_t)MTOT * KTOT;                  // 16,777,216
  const size_t WQ_BYTES = (size_t)WINDOW * FEAT * DIM;          //  5,242,880
  const size_t SX_BYTES = (size_t)MTOT * 4;                     //     65,536
  const size_t SW_BYTES = (size_t)WINDOW * FEAT * 4;            //     20,480
  signed char* xq = (signed char*)ws;
  signed char* wq = (signed char*)(ws + XQ_BYTES);
  float* sx   = (float*)(ws + XQ_BYTES + WQ_BYTES);
  float* sw   = (float*)(ws + XQ_BYTES + WQ_BYTES + SX_BYTES);
  float* part = (float*)(ws + XQ_BYTES + WQ_BYTES + SX_BYTES + SW_BYTES);

  hipLaunchKernelGGL(quant_x, dim3(MTOT / 4), dim3(256), 0, stream, x, xq, sx);
  hipLaunchKernelGGL(w_colamax_part, dim3(1, DIM / DCHUNK, WINDOW), dim3(256), 0, stream,
                     Ws, part);
  hipLaunchKernelGGL(w_colamax_reduce, dim3(NTOT / 256), dim3(256), 0, stream, part, sw);
  hipLaunchKernelGGL(transq_ws, dim3(FEAT / 32, DIM / 32, WINDOW), dim3(32, 8), 0, stream,
                     Ws, sw, wq);
  hipLaunchKernelGGL(fused_gemm_scan, dim3(BATCH * 16), dim3(512), 0, stream,
                     xq, wq, sx, sw, b, out);
}